// Round 1
// baseline (302.612 us; speedup 1.0000x reference)
//
#include <hip/hip_runtime.h>

// Bilinear warp (grid_sample align_corners=True, padding_mode='border').
// src: [B=8, C=16, H=512, W=512] f32, flow: [B, 2, H, W] f32 -> out [B,C,H,W] f32.
// Normalize/unnormalize in the reference cancels exactly: py = clip(h+flow0, 0, H-1).
//
// R1: XCD-chunked blockIdx swizzle. Without it, output rows h and h+1 are
// produced by adjacent blocks that round-robin onto DIFFERENT XCDs, so every
// src row is fetched into two non-coherent L2s (measured 2.06x src over-fetch).
// Chunked swizzle gives each XCD a contiguous run of rows -> y1/y0 vertical
// reuse hits the same L2. Flow loads and out stores are touch-once ->
// nontemporal, preserving L2 capacity for src rows.

#define BB 8
#define CC 16
#define HH 512
#define WW 512

__global__ __launch_bounds__(256) void warp_kernel(
    const float* __restrict__ src,
    const float* __restrict__ flow,
    float* __restrict__ out)
{
    const int HW = HH * WW;              // 262144
    const int NWG = (BB * HW) / 256;     // 8192 workgroups, divisible by 8
    const int CHUNK = NWG / 8;           // 1024 per XCD

    // bijective XCD-chunked swizzle: XCD k gets work items [k*CHUNK, (k+1)*CHUNK)
    int bid = (int)blockIdx.x;
    int swz = (bid & 7) * CHUNK + (bid >> 3);
    int idx = swz * 256 + (int)threadIdx.x;   // pixel index in [0, B*H*W)

    int b  = idx >> 18;          // / (512*512)
    int hw = idx & (HW - 1);
    int h  = hw >> 9;            // / 512
    int w  = hw & (WW - 1);

    const float* fb = flow + (size_t)b * 2 * HW;
    float f0 = __builtin_nontemporal_load(fb + hw);        // y displacement
    float f1 = __builtin_nontemporal_load(fb + HW + hw);   // x displacement

    float py = fminf(fmaxf((float)h + f0, 0.0f), (float)(HH - 1));
    float px = fminf(fmaxf((float)w + f1, 0.0f), (float)(WW - 1));

    float y0f = floorf(py);
    float x0f = floorf(px);
    float wy = py - y0f;
    float wx = px - x0f;

    int y0 = (int)y0f;
    int x0 = (int)x0f;
    int y1 = min(y0 + 1, HH - 1);
    int x1 = min(x0 + 1, WW - 1);

    float w00 = (1.0f - wy) * (1.0f - wx);
    float w01 = (1.0f - wy) * wx;
    float w10 = wy * (1.0f - wx);
    float w11 = wy * wx;

    int o00 = y0 * WW + x0;
    int o01 = y0 * WW + x1;
    int o10 = y1 * WW + x0;
    int o11 = y1 * WW + x1;

    const float* sb = src + (size_t)b * CC * HW;
    float*       ob = out + (size_t)b * CC * HW;

    #pragma unroll
    for (int c = 0; c < CC; ++c) {
        const float* sc = sb + c * HW;
        float v = sc[o00] * w00 + sc[o01] * w01
                + sc[o10] * w10 + sc[o11] * w11;
        __builtin_nontemporal_store(v, ob + c * HW + hw);
    }
}

extern "C" void kernel_launch(void* const* d_in, const int* in_sizes, int n_in,
                              void* d_out, int out_size, void* d_ws, size_t ws_size,
                              hipStream_t stream) {
    const float* src  = (const float*)d_in[0];
    const float* flow = (const float*)d_in[1];
    float* out = (float*)d_out;

    const int n_pix = BB * HH * WW;          // 2,097,152
    dim3 block(256);
    dim3 grid(n_pix / 256);                  // 8192 blocks (exact)
    warp_kernel<<<grid, block, 0, stream>>>(src, flow, out);
}

// Round 2
// 292.174 us; speedup vs baseline: 1.0357x; 1.0357x over previous
//
#include <hip/hip_runtime.h>

// Bilinear warp (grid_sample align_corners=True, padding_mode='border').
// src: [B=8, C=16, H=512, W=512] f32, flow: [B, 2, H, W] f32 -> out [B,C,H,W] f32.
//
// R1: XCD-chunked blockIdx swizzle (kept) — halved HBM fetch (286->74 MB) but
// time was flat => kernel is TA/L1-transaction-bound on the divergent gather,
// not HBM-bound.
// R2: halve gather instruction count. Each tap-pair (y, x0) and (y, x0+1) is
// loaded as ONE unaligned float2 (global_load_dwordx2) instead of two dword
// gathers. Border is handled weight-exactly with xl=min(x0,W-2), wx'=px-xl
// (at px=511, wx'=1 puts all weight on col 511) — no per-tap clamps/selects.
// Gathers per thread: 64 -> 32, per-instruction line footprint unchanged
// => TA transaction count ~halves.

#define BB 8
#define CC 16
#define HH 512
#define WW 512

// 8-byte vector with declared 4-byte alignment so the compiler may emit a
// single global_load_dwordx2 at any dword-aligned address.
typedef float f2u __attribute__((ext_vector_type(2), aligned(4)));

__global__ __launch_bounds__(256) void warp_kernel(
    const float* __restrict__ src,
    const float* __restrict__ flow,
    float* __restrict__ out)
{
    const int HW = HH * WW;              // 262144
    const int NWG = (BB * HW) / 256;     // 8192 workgroups, divisible by 8
    const int CHUNK = NWG / 8;           // 1024 per XCD

    // bijective XCD-chunked swizzle: XCD k gets work items [k*CHUNK, (k+1)*CHUNK)
    int bid = (int)blockIdx.x;
    int swz = (bid & 7) * CHUNK + (bid >> 3);
    int idx = swz * 256 + (int)threadIdx.x;   // pixel index in [0, B*H*W)

    int b  = idx >> 18;          // / (512*512)
    int hw = idx & (HW - 1);
    int h  = hw >> 9;            // / 512
    int w  = hw & (WW - 1);

    const float* fb = flow + (size_t)b * 2 * HW;
    float f0 = __builtin_nontemporal_load(fb + hw);        // y displacement
    float f1 = __builtin_nontemporal_load(fb + HW + hw);   // x displacement

    float py = fminf(fmaxf((float)h + f0, 0.0f), (float)(HH - 1));
    float px = fminf(fmaxf((float)w + f1, 0.0f), (float)(WW - 1));

    // Border-exact reformulation: clamp the low corner to H-2/W-2 and let the
    // fractional weight exceed toward 1. At py=511: yl=510, wy=1 -> full
    // weight on row 511 (identical result to wy=0 on row pair (511,511)).
    int yl = min((int)py, HH - 2);       // py >= 0, so (int) == floor
    int xl = min((int)px, WW - 2);
    float wy = py - (float)yl;
    float wx = px - (float)xl;

    float w00 = (1.0f - wy) * (1.0f - wx);
    float w01 = (1.0f - wy) * wx;
    float w10 = wy * (1.0f - wx);
    float w11 = wy * wx;

    int u0 = yl * WW + xl;               // low row, cols [xl, xl+1]
    int u1 = u0 + WW;                    // high row (yl+1 <= 511)

    const float* sb = src + (size_t)b * CC * HW;
    float*       ob = out + (size_t)b * CC * HW;

    #pragma unroll
    for (int c = 0; c < CC; ++c) {
        const float* sc = sb + c * HW;
        f2u r0 = *reinterpret_cast<const f2u*>(sc + u0);   // {v00, v01}
        f2u r1 = *reinterpret_cast<const f2u*>(sc + u1);   // {v10, v11}
        float v = r0.x * w00 + r0.y * w01
                + r1.x * w10 + r1.y * w11;
        __builtin_nontemporal_store(v, ob + c * HW + hw);
    }
}

extern "C" void kernel_launch(void* const* d_in, const int* in_sizes, int n_in,
                              void* d_out, int out_size, void* d_ws, size_t ws_size,
                              hipStream_t stream) {
    const float* src  = (const float*)d_in[0];
    const float* flow = (const float*)d_in[1];
    float* out = (float*)d_out;

    const int n_pix = BB * HH * WW;          // 2,097,152
    dim3 block(256);
    dim3 grid(n_pix / 256);                  // 8192 blocks (exact)
    warp_kernel<<<grid, block, 0, stream>>>(src, flow, out);
}

// Round 4
// 283.917 us; speedup vs baseline: 1.0658x; 1.0291x over previous
//
#include <hip/hip_runtime.h>

// Bilinear warp (grid_sample align_corners=True, padding_mode='border').
// src: [B=8, C=16, H=512, W=512] f32, flow: [B, 2, H, W] f32 -> out [B,C,H,W] f32.
//
// R1: XCD-chunked blockIdx swizzle (kept) — halved HBM fetch (286->74 MB), time flat.
// R2: float2 tap-pair gathers (kept) — 64->32 gather instrs, only -7%.
//     Post-mortem: all pipes <21% busy, 3x above the TA transaction floor
//     => LATENCY-bound. VGPR=36 means the compiler serialized the channel
//     loop into tiny load batches (~8 outstanding loads/wave).
// R3: preload ALL 32 tap-pair gathers into register arrays before any use
//     (full unroll + sched_barrier pin). VGPR ~100 halves occupancy but
//     triples in-flight loads per CU (176 -> ~512) — trading occupancy for
//     MLP, the right trade when latency-bound with idle pipes.
//     (R3 bench was an infra failure — container died twice; resubmitting.)

#define BB 8
#define CC 16
#define HH 512
#define WW 512

// 8-byte vector with declared 4-byte alignment so the compiler may emit a
// single global_load_dwordx2 at any dword-aligned address.
typedef float f2u __attribute__((ext_vector_type(2), aligned(4)));

__global__ __launch_bounds__(256) void warp_kernel(
    const float* __restrict__ src,
    const float* __restrict__ flow,
    float* __restrict__ out)
{
    const int HW = HH * WW;              // 262144
    const int NWG = (BB * HW) / 256;     // 8192 workgroups, divisible by 8
    const int CHUNK = NWG / 8;           // 1024 per XCD

    // bijective XCD-chunked swizzle: XCD k gets work items [k*CHUNK, (k+1)*CHUNK)
    int bid = (int)blockIdx.x;
    int swz = (bid & 7) * CHUNK + (bid >> 3);
    int idx = swz * 256 + (int)threadIdx.x;   // pixel index in [0, B*H*W)

    int b  = idx >> 18;          // / (512*512)
    int hw = idx & (HW - 1);
    int h  = hw >> 9;            // / 512
    int w  = hw & (WW - 1);

    const float* fb = flow + (size_t)b * 2 * HW;
    float f0 = __builtin_nontemporal_load(fb + hw);        // y displacement
    float f1 = __builtin_nontemporal_load(fb + HW + hw);   // x displacement

    float py = fminf(fmaxf((float)h + f0, 0.0f), (float)(HH - 1));
    float px = fminf(fmaxf((float)w + f1, 0.0f), (float)(WW - 1));

    // Border-exact reformulation: clamp the low corner to H-2/W-2 and let the
    // fractional weight reach 1. At py=511: yl=510, wy=1 -> full weight on
    // row 511 (identical result). No per-tap clamps needed.
    int yl = min((int)py, HH - 2);       // py >= 0, so (int) == floor
    int xl = min((int)px, WW - 2);
    float wy = py - (float)yl;
    float wx = px - (float)xl;

    float w00 = (1.0f - wy) * (1.0f - wx);
    float w01 = (1.0f - wy) * wx;
    float w10 = wy * (1.0f - wx);
    float w11 = wy * wx;

    int u0 = yl * WW + xl;               // low row, cols [xl, xl+1]
    int u1 = u0 + WW;                    // high row (yl+1 <= 511)

    const float* sb = src + (size_t)b * CC * HW;
    float*       ob = out + (size_t)b * CC * HW;

    // Phase 1: issue ALL 32 independent gathers (2 per channel). Register
    // arrays with compile-time indices stay in VGPRs after full unroll.
    f2u r0[CC], r1[CC];
    #pragma unroll
    for (int c = 0; c < CC; ++c) {
        const float* sc = sb + c * HW;
        r0[c] = *reinterpret_cast<const f2u*>(sc + u0);   // {v00, v01}
        r1[c] = *reinterpret_cast<const f2u*>(sc + u1);   // {v10, v11}
    }
    // Pin the schedule: no compute sinks above, no loads sink below. Keeps
    // all 32 loads in flight before the first s_waitcnt-forcing use.
    __builtin_amdgcn_sched_barrier(0);

    // Phase 2: weighted sums + coalesced nontemporal stores. Uses consume
    // loads oldest-first, so vmcnt waits stay shallow.
    #pragma unroll
    for (int c = 0; c < CC; ++c) {
        float v = r0[c].x * w00 + r0[c].y * w01
                + r1[c].x * w10 + r1[c].y * w11;
        __builtin_nontemporal_store(v, ob + c * HW + hw);
    }
}

extern "C" void kernel_launch(void* const* d_in, const int* in_sizes, int n_in,
                              void* d_out, int out_size, void* d_ws, size_t ws_size,
                              hipStream_t stream) {
    const float* src  = (const float*)d_in[0];
    const float* flow = (const float*)d_in[1];
    float* out = (float*)d_out;

    const int n_pix = BB * HH * WW;          // 2,097,152
    dim3 block(256);
    dim3 grid(n_pix / 256);                  // 8192 blocks (exact)
    warp_kernel<<<grid, block, 0, stream>>>(src, flow, out);
}